// Round 1
// baseline (581.281 us; speedup 1.0000x reference)
//
#include <hip/hip_runtime.h>
#include <hip/hip_bf16.h>
#include <cstdint>

// ---------------------------------------------------------------------------
// Problem constants (from reference): N=50000, E=600000, D_IN=256, H1=128,
// H2=64, DK=64, HEADS=2 (dk=32, scale=1/sqrt(32)). All fp32 this round.
// ---------------------------------------------------------------------------

// ---------------- CSR build --------------------------------------------------

__global__ void hist_kernel(const int* __restrict__ rows, int* __restrict__ cnt, int E) {
    int i = blockIdx.x * blockDim.x + threadIdx.x;
    if (i < E) atomicAdd(&cnt[rows[i]], 1);
}

__global__ void scan1_kernel(const int* __restrict__ cnt, int* __restrict__ excl,
                             int* __restrict__ bsum, int N) {
    __shared__ int sh[256];
    int t = threadIdx.x;
    int i = blockIdx.x * 256 + t;
    int v = (i < N) ? cnt[i] : 0;
    sh[t] = v;
    __syncthreads();
    for (int off = 1; off < 256; off <<= 1) {
        int x = (t >= off) ? sh[t - off] : 0;
        __syncthreads();
        sh[t] += x;
        __syncthreads();
    }
    if (i < N) excl[i] = sh[t] - v;          // exclusive within block
    if (t == 255) bsum[blockIdx.x] = sh[255]; // block total
}

__global__ void scan2_kernel(int* __restrict__ bsum, int nb) {
    __shared__ int sh[256];
    int t = threadIdx.x;
    int v = (t < nb) ? bsum[t] : 0;
    sh[t] = v;
    __syncthreads();
    for (int off = 1; off < 256; off <<= 1) {
        int x = (t >= off) ? sh[t - off] : 0;
        __syncthreads();
        sh[t] += x;
        __syncthreads();
    }
    if (t < nb) bsum[t] = sh[t] - v; // exclusive block offsets
}

__global__ void scan3_kernel(const int* __restrict__ excl, const int* __restrict__ bsum,
                             int* __restrict__ row_start, int* __restrict__ cursor,
                             int N, int E) {
    int i = blockIdx.x * 256 + threadIdx.x;
    if (i < N) {
        int v = excl[i] + bsum[i >> 8];
        row_start[i] = v;
        cursor[i] = v;
    }
    if (i == 0) row_start[N] = E;
}

__global__ void scatter_kernel(const int* __restrict__ rows, const int* __restrict__ colsIn,
                               const float* __restrict__ valsIn, int* __restrict__ cursor,
                               int* __restrict__ colsOut, float* __restrict__ valsOut, int E) {
    int i = blockIdx.x * blockDim.x + threadIdx.x;
    if (i < E) {
        int r = rows[i];
        int p = atomicAdd(&cursor[r], 1);
        colsOut[p] = colsIn[i];
        valsOut[p] = valsIn[i];
    }
}

// ---------------- Generic fp32 tiled GEMM (+optional leaky-relu, dual-W) ----
// C[M,BN] = act(A[M,K] @ W)   with W = W0 [K,BN]  or  [W0 | W1] each [K,BN/2]

template<int K, int BN, bool RELU, bool DUAL>
__global__ __launch_bounds__(256) void gemm_kernel(
    const float* __restrict__ A, const float* __restrict__ W0,
    const float* __restrict__ W1, float* __restrict__ C, int M)
{
    constexpr int BM = 64;
    constexpr int BK = 64;
    constexpr int TN = 4;
    constexpr int TCOLS = BN / TN;     // 32 (BN=128) or 16 (BN=64)
    constexpr int TROWS = 256 / TCOLS; // 8 or 16
    constexpr int TM = BM / TROWS;     // 8 or 4

    __shared__ __align__(16) float As[BM][BK + 4];
    __shared__ __align__(16) float Ws[BK][BN];

    const int tid = threadIdx.x;
    const int tx = tid % TCOLS;
    const int ty = tid / TCOLS;
    const int r0 = blockIdx.x * BM;

    float acc[TM][TN];
#pragma unroll
    for (int i = 0; i < TM; ++i)
#pragma unroll
        for (int j = 0; j < TN; ++j) acc[i][j] = 0.f;

    for (int kc = 0; kc < K; kc += BK) {
        // stage A tile: 64x64 floats = 1024 float4 over 256 threads
#pragma unroll
        for (int l = 0; l < 4; ++l) {
            int f = tid + 256 * l;
            int row = f >> 4;
            int kp = (f & 15) << 2;
            float4 val = make_float4(0.f, 0.f, 0.f, 0.f);
            int grow = r0 + row;
            if (grow < M)
                val = *reinterpret_cast<const float4*>(&A[(size_t)grow * K + kc + kp]);
            *reinterpret_cast<float4*>(&As[row][kp]) = val;
        }
        // stage W tile
        if constexpr (!DUAL) {
            constexpr int F4 = BK * BN / 4;
#pragma unroll
            for (int l = 0; l < F4 / 256; ++l) {
                int f = tid + 256 * l;
                int kk = f / (BN / 4);
                int jp = (f % (BN / 4)) * 4;
                *reinterpret_cast<float4*>(&Ws[kk][jp]) =
                    *reinterpret_cast<const float4*>(&W0[(size_t)(kc + kk) * BN + jp]);
            }
        } else {
            // BN==128, two [K,64] weights side-by-side
#pragma unroll
            for (int l = 0; l < 4; ++l) {
                int f = tid + 256 * l;
                int kk = f >> 4;
                int jp = (f & 15) << 2;
                *reinterpret_cast<float4*>(&Ws[kk][jp]) =
                    *reinterpret_cast<const float4*>(&W0[(size_t)(kc + kk) * 64 + jp]);
                *reinterpret_cast<float4*>(&Ws[kk][64 + jp]) =
                    *reinterpret_cast<const float4*>(&W1[(size_t)(kc + kk) * 64 + jp]);
            }
        }
        __syncthreads();

#pragma unroll 8
        for (int kk = 0; kk < BK; ++kk) {
            float a[TM], wv[TN];
#pragma unroll
            for (int i = 0; i < TM; ++i) a[i] = As[ty * TM + i][kk];
#pragma unroll
            for (int j = 0; j < TN; ++j) wv[j] = Ws[kk][tx + TCOLS * j];
#pragma unroll
            for (int i = 0; i < TM; ++i)
#pragma unroll
                for (int j = 0; j < TN; ++j) acc[i][j] = fmaf(a[i], wv[j], acc[i][j]);
        }
        __syncthreads();
    }

#pragma unroll
    for (int i = 0; i < TM; ++i) {
        int row = r0 + ty * TM + i;
        if (row < M) {
#pragma unroll
            for (int j = 0; j < TN; ++j) {
                float v = acc[i][j];
                if (RELU) v = v > 0.f ? v : 0.01f * v;
                C[(size_t)row * BN + tx + TCOLS * j] = v;
            }
        }
    }
}

// ---------------- SpMM over CSR, 128-wide features, leaky-relu epilogue -----
// SPLIT: cols 0..63 -> out0 (mu), 64..127 -> out1 (var), each [N,64]

template<bool SPLIT>
__global__ __launch_bounds__(128) void spmm_kernel(
    const int* __restrict__ row_start, const int* __restrict__ cols,
    const float* __restrict__ vals, const float* __restrict__ X,
    float* __restrict__ out0, float* __restrict__ out1, int N)
{
    int r = blockIdx.x;
    int t = threadIdx.x;
    int s = row_start[r];
    int e = row_start[r + 1];
    float acc = 0.f;
    for (int i = s; i < e; ++i) {
        int c = cols[i];
        float v = vals[i];
        acc = fmaf(v, X[(size_t)c * 128 + t], acc);
    }
    float o = acc > 0.f ? acc : 0.01f * acc;
    if constexpr (!SPLIT) {
        out0[(size_t)r * 128 + t] = o;
    } else {
        if (t < 64) out0[(size_t)r * 64 + t] = o;
        else        out1[(size_t)r * 64 + (t - 64)] = o;
    }
}

// ---------------- K/V projection of condition -------------------------------
// Kt layout: [head][d(32)][key(128)]   (transposed for conflict-free logits)
// Vm layout: [head][key(128)][d(32)]

__global__ __launch_bounds__(128) void kv_kernel(
    const float* __restrict__ cond, const float* __restrict__ Wk,
    const float* __restrict__ Wv, float* __restrict__ Kt, float* __restrict__ Vm)
{
    int j = blockIdx.x;      // key index 0..127
    int t = threadIdx.x;     // 0..127
    __shared__ float c[128];
    c[t] = cond[j * 128 + t];
    __syncthreads();
    const float* W = (t < 64) ? Wk : Wv;
    int col = t & 63;
    float acc = 0.f;
#pragma unroll 8
    for (int k = 0; k < 128; ++k) acc = fmaf(c[k], W[k * 64 + col], acc);
    int h = col >> 5, d = col & 31;
    if (t < 64) Kt[(h * 32 + d) * 128 + j] = acc;
    else        Vm[(h * 128 + j) * 32 + d] = acc;
}

// ---------------- Per-node attention (one wave per node) --------------------
// logits[h][j] = scale * sum_d Q[n][32h+d] * K[j][32h+d];  softmax over j(128)
// ctx[n][32h+d] = sum_j w[h][j] * V[j][32h+d]

__global__ __launch_bounds__(256) void attn_kernel(
    const float* __restrict__ Q, const float* __restrict__ Kt,
    const float* __restrict__ Vm, float* __restrict__ ctx, int N)
{
    __shared__ float Kl[2 * 32 * 128];
    __shared__ float Vl[2 * 128 * 32];
    __shared__ float Ql[4][64];
    __shared__ float Wl[4][256];

    const int tid = threadIdx.x;
    for (int i = tid; i < 8192; i += 256) Kl[i] = Kt[i];
    for (int i = tid; i < 8192; i += 256) Vl[i] = Vm[i];

    const int wave = tid >> 6, lane = tid & 63;
    int nid = blockIdx.x * 4 + wave;
    bool valid = nid < N;
    int n = valid ? nid : N - 1;

    float q = Q[(size_t)n * 64 + lane] * 0.17677669529663687f; // dk^-0.5, dk=32
    Ql[wave][lane] = q;
    __syncthreads();

    float lg0 = 0.f, lg1 = 0.f, lg2 = 0.f, lg3 = 0.f;
#pragma unroll 8
    for (int d = 0; d < 32; ++d) {
        float q0 = Ql[wave][d];
        float q1 = Ql[wave][32 + d];
        float k0 = Kl[d * 128 + lane];
        float k1 = Kl[d * 128 + 64 + lane];
        float k2 = Kl[(32 + d) * 128 + lane];
        float k3 = Kl[(32 + d) * 128 + 64 + lane];
        lg0 = fmaf(q0, k0, lg0);
        lg1 = fmaf(q0, k1, lg1);
        lg2 = fmaf(q1, k2, lg2);
        lg3 = fmaf(q1, k3, lg3);
    }
    // softmax: head0 -> {lg0:j=lane, lg1:j=64+lane}, head1 -> {lg2, lg3}
    float m0 = fmaxf(lg0, lg1);
    float m1 = fmaxf(lg2, lg3);
#pragma unroll
    for (int off = 32; off > 0; off >>= 1) {
        m0 = fmaxf(m0, __shfl_xor(m0, off, 64));
        m1 = fmaxf(m1, __shfl_xor(m1, off, 64));
    }
    float e0 = __expf(lg0 - m0), e1 = __expf(lg1 - m0);
    float e2 = __expf(lg2 - m1), e3 = __expf(lg3 - m1);
    float s0 = e0 + e1, s1 = e2 + e3;
#pragma unroll
    for (int off = 32; off > 0; off >>= 1) {
        s0 += __shfl_xor(s0, off, 64);
        s1 += __shfl_xor(s1, off, 64);
    }
    float is0 = 1.0f / s0, is1 = 1.0f / s1;
    Wl[wave][lane]       = e0 * is0;
    Wl[wave][64 + lane]  = e1 * is0;
    Wl[wave][128 + lane] = e2 * is1;
    Wl[wave][192 + lane] = e3 * is1;
    __syncthreads();

    const int h = lane >> 5, d = lane & 31;
    float acc0 = 0.f, acc1 = 0.f;
#pragma unroll 8
    for (int j = 0; j < 128; j += 2) {
        float w0 = Wl[wave][h * 128 + j];
        float w1 = Wl[wave][h * 128 + j + 1];
        acc0 = fmaf(w0, Vl[(h * 128 + j) * 32 + d], acc0);
        acc1 = fmaf(w1, Vl[(h * 128 + j + 1) * 32 + d], acc1);
    }
    if (valid) ctx[(size_t)n * 64 + lane] = acc0 + acc1;
}

// ---------------------------------------------------------------------------

extern "C" void kernel_launch(void* const* d_in, const int* in_sizes, int n_in,
                              void* d_out, int out_size, void* d_ws, size_t ws_size,
                              hipStream_t stream)
{
    const float* ns_emb   = (const float*)d_in[0];
    const int*   erows    = (const int*)d_in[1];
    const int*   ecols    = (const int*)d_in[2];
    const float* evals    = (const float*)d_in[3];
    const float* cond     = (const float*)d_in[4];
    const float* W_hidden = (const float*)d_in[5];
    const float* W_mu     = (const float*)d_in[6];
    const float* W_var    = (const float*)d_in[7];
    const float* Wq       = (const float*)d_in[8];
    const float* Wk       = (const float*)d_in[9];
    const float* Wv       = (const float*)d_in[10];
    const float* Wo       = (const float*)d_in[11];

    const int N = in_sizes[0] / 256;  // 50000
    const int E = in_sizes[1];        // 600000

    uint8_t* p = (uint8_t*)d_ws;
    auto alloc = [&](size_t bytes) {
        uint8_t* r = p;
        p += (bytes + 255) & ~(size_t)255;
        return r;
    };
    float* bufA      = (float*)alloc(sizeof(float) * (size_t)N * 128); // support1 / attended
    float* bufB      = (float*)alloc(sizeof(float) * (size_t)N * 128); // hidden / supp_muvar
    float* Qb        = (float*)alloc(sizeof(float) * (size_t)N * 64);
    float* ctxb      = (float*)alloc(sizeof(float) * (size_t)N * 64);
    float* Kt        = (float*)alloc(sizeof(float) * 8192);
    float* Vm        = (float*)alloc(sizeof(float) * 8192);
    int*   cnt       = (int*)alloc(sizeof(int) * N);
    int*   excl      = (int*)alloc(sizeof(int) * N);
    int*   bsum      = (int*)alloc(sizeof(int) * 256);
    int*   row_start = (int*)alloc(sizeof(int) * (N + 1));
    int*   cursor    = (int*)alloc(sizeof(int) * N);
    int*   scol      = (int*)alloc(sizeof(int) * E);
    float* sval      = (float*)alloc(sizeof(float) * E);

    // ---- CSR build (inputs restored & ws poisoned every launch) ----
    hipMemsetAsync(cnt, 0, sizeof(int) * N, stream);
    hist_kernel<<<(E + 255) / 256, 256, 0, stream>>>(erows, cnt, E);
    int nb = (N + 255) / 256;
    scan1_kernel<<<nb, 256, 0, stream>>>(cnt, excl, bsum, N);
    scan2_kernel<<<1, 256, 0, stream>>>(bsum, nb);
    scan3_kernel<<<nb, 256, 0, stream>>>(excl, bsum, row_start, cursor, N, E);
    scatter_kernel<<<(E + 255) / 256, 256, 0, stream>>>(erows, ecols, evals, cursor,
                                                        scol, sval, E);

    int gblocks = (N + 63) / 64;

    // ---- GCN1: support1 = lrelu(ns_emb @ W_hidden); hidden = lrelu(spmm) ----
    gemm_kernel<256, 128, true, false><<<gblocks, 256, 0, stream>>>(
        ns_emb, W_hidden, nullptr, bufA, N);
    spmm_kernel<false><<<N, 128, 0, stream>>>(row_start, scol, sval, bufA, bufB, nullptr, N);

    // ---- Attention ----
    kv_kernel<<<128, 128, 0, stream>>>(cond, Wk, Wv, Kt, Vm);
    gemm_kernel<128, 64, false, false><<<gblocks, 256, 0, stream>>>(
        bufB, Wq, nullptr, Qb, N);
    attn_kernel<<<(N + 3) / 4, 256, 0, stream>>>(Qb, Kt, Vm, ctxb, N);
    gemm_kernel<64, 128, false, false><<<gblocks, 256, 0, stream>>>(
        ctxb, Wo, nullptr, bufA, N);  // attended

    // ---- GCN2/3 fused: [lrelu(att@W_mu) | lrelu(att@W_var)] then spmm ----
    gemm_kernel<128, 128, true, true><<<gblocks, 256, 0, stream>>>(
        bufA, W_mu, W_var, bufB, N);
    float* out = (float*)d_out;
    spmm_kernel<true><<<N, 128, 0, stream>>>(row_start, scol, sval, bufB,
                                             out, out + (size_t)N * 64, N);
}

// Round 2
// 496.990 us; speedup vs baseline: 1.1696x; 1.1696x over previous
//
#include <hip/hip_runtime.h>
#include <hip/hip_bf16.h>
#include <cstdint>

// ---------------------------------------------------------------------------
// N=50000, E=600000, D_IN=256, H1=128, H2=64, DK=64, HEADS=2 (dk=32).
// R2: all dense GEMMs via one bf16 MFMA kernel; attention folded into GEMMs
// with block-diagonal K/V matrices (K/V shared across all nodes).
// ---------------------------------------------------------------------------

typedef __attribute__((ext_vector_type(8))) short short8;
typedef __attribute__((ext_vector_type(4))) float f32x4;
typedef __attribute__((ext_vector_type(4))) unsigned short ushort4_t;

__device__ __forceinline__ unsigned short f2bf(float f) {
    unsigned int u = __builtin_bit_cast(unsigned int, f);
    u += 0x7fffu + ((u >> 16) & 1u);   // round-to-nearest-even
    return (unsigned short)(u >> 16);
}

// ---------------- CSR build --------------------------------------------------

__global__ void hist_kernel(const int* __restrict__ rows, int* __restrict__ cnt, int E) {
    int i = blockIdx.x * blockDim.x + threadIdx.x;
    if (i < E) atomicAdd(&cnt[rows[i]], 1);
}

__global__ void scan1_kernel(const int* __restrict__ cnt, int* __restrict__ excl,
                             int* __restrict__ bsum, int N) {
    __shared__ int sh[256];
    int t = threadIdx.x;
    int i = blockIdx.x * 256 + t;
    int v = (i < N) ? cnt[i] : 0;
    sh[t] = v;
    __syncthreads();
    for (int off = 1; off < 256; off <<= 1) {
        int x = (t >= off) ? sh[t - off] : 0;
        __syncthreads();
        sh[t] += x;
        __syncthreads();
    }
    if (i < N) excl[i] = sh[t] - v;
    if (t == 255) bsum[blockIdx.x] = sh[255];
}

__global__ void scan2_kernel(int* __restrict__ bsum, int nb) {
    __shared__ int sh[256];
    int t = threadIdx.x;
    int v = (t < nb) ? bsum[t] : 0;
    sh[t] = v;
    __syncthreads();
    for (int off = 1; off < 256; off <<= 1) {
        int x = (t >= off) ? sh[t - off] : 0;
        __syncthreads();
        sh[t] += x;
        __syncthreads();
    }
    if (t < nb) bsum[t] = sh[t] - v;
}

__global__ void scan3_kernel(const int* __restrict__ excl, const int* __restrict__ bsum,
                             int* __restrict__ row_start, int* __restrict__ cursor,
                             int N, int E) {
    int i = blockIdx.x * 256 + threadIdx.x;
    if (i < N) {
        int v = excl[i] + bsum[i >> 8];
        row_start[i] = v;
        cursor[i] = v;
    }
    if (i == 0) row_start[N] = E;
}

__global__ void scatter_kernel(const int* __restrict__ rows, const int* __restrict__ colsIn,
                               const float* __restrict__ valsIn, int* __restrict__ cursor,
                               int* __restrict__ colsOut, float* __restrict__ valsOut, int E) {
    int i = blockIdx.x * blockDim.x + threadIdx.x;
    if (i < E) {
        int r = rows[i];
        int p = atomicAdd(&cursor[r], 1);
        colsOut[p] = colsIn[i];
        valsOut[p] = valsIn[i];
    }
}

// ---------------- bf16 MFMA GEMM --------------------------------------------
// C[M, *] = act(A[M,K] @ B).  BM=128, BN=64 per block, BK=64 per stage.
// A fp32 [M,K] lda; B fp32 [K,*] ldb (col offset n0 unless dual); C fp32 ldc.
// dual: gridDim.y==2, block y==1 uses B1 with local cols (for [W_mu | W_var]).
// 4 waves: wave (wm,wn) owns 64x32 quadrant -> 4x2 fragments of 16x16.
// LDS stride 72 shorts (144 B): 2-way bank aliasing only (free).

__global__ __launch_bounds__(256) void mfma_gemm(
    const float* __restrict__ A, const float* __restrict__ B0,
    const float* __restrict__ B1, float* __restrict__ C,
    int M, int K, int lda, int ldb, int ldc, int relu, int dual)
{
    __shared__ unsigned short As[128][72];
    __shared__ unsigned short Bs[64][72];

    const int tid = threadIdx.x;
    const int lane = tid & 63, wave = tid >> 6;
    const int wm = wave & 1, wn = wave >> 1;
    const int r0 = blockIdx.x * 128;
    const int n0 = blockIdx.y * 64;

    const float* Bp = B0;
    int bn0 = n0;
    if (dual && blockIdx.y == 1) { Bp = B1; bn0 = 0; }

    f32x4 acc[4][2];
#pragma unroll
    for (int mt = 0; mt < 4; ++mt)
#pragma unroll
        for (int nt = 0; nt < 2; ++nt)
#pragma unroll
            for (int r = 0; r < 4; ++r) acc[mt][nt][r] = 0.f;

    for (int kc = 0; kc < K; kc += 64) {
        // stage A: 128x64 fp32 -> bf16, 2048 float4 over 256 threads
#pragma unroll
        for (int i = 0; i < 8; ++i) {
            int f = tid + 256 * i;
            int row = f >> 4;
            int kq = (f & 15) << 2;
            int gr = r0 + row;
            if (gr >= M) gr = M - 1;                    // clamp; stores guarded
            float4 v = *reinterpret_cast<const float4*>(&A[(size_t)gr * lda + kc + kq]);
            ushort4_t pv;
            pv[0] = f2bf(v.x); pv[1] = f2bf(v.y); pv[2] = f2bf(v.z); pv[3] = f2bf(v.w);
            *reinterpret_cast<ushort4_t*>(&As[row][kq]) = pv;
        }
        // stage B transposed: Bs[n][k] <- B[kc+k][bn0+n]
#pragma unroll
        for (int i = 0; i < 16; ++i) {
            int k = (tid >> 6) + 4 * i;
            int n = tid & 63;
            Bs[n][k] = f2bf(Bp[(size_t)(kc + k) * ldb + bn0 + n]);
        }
        __syncthreads();

#pragma unroll
        for (int ks = 0; ks < 2; ++ks) {
            const int koff = ks * 32 + (lane >> 4) * 8;
            short8 a[4], b[2];
#pragma unroll
            for (int mt = 0; mt < 4; ++mt)
                a[mt] = *reinterpret_cast<const short8*>(&As[wm * 64 + mt * 16 + (lane & 15)][koff]);
#pragma unroll
            for (int nt = 0; nt < 2; ++nt)
                b[nt] = *reinterpret_cast<const short8*>(&Bs[wn * 32 + nt * 16 + (lane & 15)][koff]);
#pragma unroll
            for (int mt = 0; mt < 4; ++mt)
#pragma unroll
                for (int nt = 0; nt < 2; ++nt)
                    acc[mt][nt] = __builtin_amdgcn_mfma_f32_16x16x32_bf16(
                        a[mt], b[nt], acc[mt][nt], 0, 0, 0);
        }
        __syncthreads();
    }

    // epilogue: C/D layout col=lane&15, row=(lane>>4)*4+r
    const int quad = lane >> 4;
#pragma unroll
    for (int mt = 0; mt < 4; ++mt) {
#pragma unroll
        for (int nt = 0; nt < 2; ++nt) {
            int gc = n0 + wn * 32 + nt * 16 + (lane & 15);
#pragma unroll
            for (int r = 0; r < 4; ++r) {
                int gr = r0 + wm * 64 + mt * 16 + quad * 4 + r;
                if (gr < M) {
                    float v = acc[mt][nt][r];
                    if (relu) v = v > 0.f ? v : 0.01f * v;
                    C[(size_t)gr * ldc + gc] = v;
                }
            }
        }
    }
}

// ---------------- SpMM over CSR, 128-wide features, leaky-relu epilogue -----

template<bool SPLIT>
__global__ __launch_bounds__(128) void spmm_kernel(
    const int* __restrict__ row_start, const int* __restrict__ cols,
    const float* __restrict__ vals, const float* __restrict__ X,
    float* __restrict__ out0, float* __restrict__ out1, int N)
{
    int r = blockIdx.x;
    int t = threadIdx.x;
    int s = row_start[r];
    int e = row_start[r + 1];
    float acc = 0.f;
    for (int i = s; i < e; ++i) {
        int c = cols[i];
        float v = vals[i];
        acc = fmaf(v, X[(size_t)c * 128 + t], acc);
    }
    float o = acc > 0.f ? acc : 0.01f * acc;
    if constexpr (!SPLIT) {
        out0[(size_t)r * 128 + t] = o;
    } else {
        if (t < 64) out0[(size_t)r * 64 + t] = o;
        else        out1[(size_t)r * 64 + (t - 64)] = o;
    }
}

// ---------------- K/V projection into block-diagonal GEMM operands ----------
// Bqk [64][256]:  Bqk[d][h*128 + j] = (cond @ Wk)[j][d],  h = d>>5
// Bpv [256][64]:  Bpv[h*128 + j][d] = (cond @ Wv)[j][d],  h = d>>5
// (off-diagonal blocks pre-zeroed by memset)

__global__ __launch_bounds__(128) void kv_kernel(
    const float* __restrict__ cond, const float* __restrict__ Wk,
    const float* __restrict__ Wv, float* __restrict__ Bqk, float* __restrict__ Bpv)
{
    int j = blockIdx.x;      // key 0..127
    int t = threadIdx.x;     // 0..127
    __shared__ float c[128];
    c[t] = cond[j * 128 + t];
    __syncthreads();
    const float* W = (t < 64) ? Wk : Wv;
    int col = t & 63;
    float acc = 0.f;
#pragma unroll 8
    for (int k = 0; k < 128; ++k) acc = fmaf(c[k], W[k * 64 + col], acc);
    int h = col >> 5;
    if (t < 64) Bqk[col * 256 + h * 128 + j] = acc;
    else        Bpv[(size_t)(h * 128 + j) * 64 + col] = acc;
}

// ---------------- In-place row softmax over logits [N,256] ------------------
// head0 = cols 0..127, head1 = cols 128..255; scale dk^-0.5 folded in.

__global__ __launch_bounds__(256) void softmax_kernel(float* __restrict__ L, int N)
{
    const int wave = threadIdx.x >> 6, lane = threadIdx.x & 63;
    int n = blockIdx.x * 4 + wave;
    if (n >= N) return;
    float* row = L + (size_t)n * 256;
    const float s = 0.17677669529663687f; // 32^-0.5
    float x0 = row[lane] * s;
    float x1 = row[64 + lane] * s;
    float x2 = row[128 + lane] * s;
    float x3 = row[192 + lane] * s;
    float m0 = fmaxf(x0, x1), m1 = fmaxf(x2, x3);
#pragma unroll
    for (int off = 32; off > 0; off >>= 1) {
        m0 = fmaxf(m0, __shfl_xor(m0, off, 64));
        m1 = fmaxf(m1, __shfl_xor(m1, off, 64));
    }
    float e0 = __expf(x0 - m0), e1 = __expf(x1 - m0);
    float e2 = __expf(x2 - m1), e3 = __expf(x3 - m1);
    float s0 = e0 + e1, s1 = e2 + e3;
#pragma unroll
    for (int off = 32; off > 0; off >>= 1) {
        s0 += __shfl_xor(s0, off, 64);
        s1 += __shfl_xor(s1, off, 64);
    }
    float i0 = 1.0f / s0, i1 = 1.0f / s1;
    row[lane]        = e0 * i0;
    row[64 + lane]   = e1 * i0;
    row[128 + lane]  = e2 * i1;
    row[192 + lane]  = e3 * i1;
}

// ---------------------------------------------------------------------------

extern "C" void kernel_launch(void* const* d_in, const int* in_sizes, int n_in,
                              void* d_out, int out_size, void* d_ws, size_t ws_size,
                              hipStream_t stream)
{
    const float* ns_emb   = (const float*)d_in[0];
    const int*   erows    = (const int*)d_in[1];
    const int*   ecols    = (const int*)d_in[2];
    const float* evals    = (const float*)d_in[3];
    const float* cond     = (const float*)d_in[4];
    const float* W_hidden = (const float*)d_in[5];
    const float* W_mu     = (const float*)d_in[6];
    const float* W_var    = (const float*)d_in[7];
    const float* Wq       = (const float*)d_in[8];
    const float* Wk       = (const float*)d_in[9];
    const float* Wv       = (const float*)d_in[10];
    const float* Wo       = (const float*)d_in[11];

    const int N = in_sizes[0] / 256;  // 50000
    const int E = in_sizes[1];        // 600000

    uint8_t* p = (uint8_t*)d_ws;
    auto alloc = [&](size_t bytes) {
        uint8_t* r = p;
        p += (bytes + 255) & ~(size_t)255;
        return r;
    };
    float* bufA      = (float*)alloc(sizeof(float) * (size_t)N * 128); // support1 / attended
    float* bufB      = (float*)alloc(sizeof(float) * (size_t)N * 128); // hidden / muvar-support
    float* Qb        = (float*)alloc(sizeof(float) * (size_t)N * 64);  // Q, then ctx
    float* logits    = (float*)alloc(sizeof(float) * (size_t)N * 256); // logits -> P in-place
    float* Bqk       = (float*)alloc(sizeof(float) * 64 * 256);
    float* Bpv       = (float*)alloc(sizeof(float) * 256 * 64);
    int*   cnt       = (int*)alloc(sizeof(int) * N);
    int*   excl      = (int*)alloc(sizeof(int) * N);
    int*   bsum      = (int*)alloc(sizeof(int) * 256);
    int*   row_start = (int*)alloc(sizeof(int) * (N + 1));
    int*   cursor    = (int*)alloc(sizeof(int) * N);
    int*   scol      = (int*)alloc(sizeof(int) * E);
    float* sval      = (float*)alloc(sizeof(float) * E);

    // ---- CSR build ----
    hipMemsetAsync(cnt, 0, sizeof(int) * N, stream);
    hist_kernel<<<(E + 255) / 256, 256, 0, stream>>>(erows, cnt, E);
    int nb = (N + 255) / 256;
    scan1_kernel<<<nb, 256, 0, stream>>>(cnt, excl, bsum, N);
    scan2_kernel<<<1, 256, 0, stream>>>(bsum, nb);
    scan3_kernel<<<nb, 256, 0, stream>>>(excl, bsum, row_start, cursor, N, E);
    scatter_kernel<<<(E + 255) / 256, 256, 0, stream>>>(erows, ecols, evals, cursor,
                                                        scol, sval, E);

    // ---- K/V operands (independent of GCN1; zero off-diagonal blocks) ----
    hipMemsetAsync(Bqk, 0, sizeof(float) * 64 * 256, stream);
    hipMemsetAsync(Bpv, 0, sizeof(float) * 256 * 64, stream);
    kv_kernel<<<128, 128, 0, stream>>>(cond, Wk, Wv, Bqk, Bpv);

    const int mb = (N + 127) / 128;  // 391

    // ---- GCN1: support1 = lrelu(ns_emb @ W_hidden); hidden = lrelu(spmm) ----
    mfma_gemm<<<dim3(mb, 2), 256, 0, stream>>>(ns_emb, W_hidden, nullptr, bufA,
                                               N, 256, 256, 128, 128, 1, 0);
    spmm_kernel<false><<<N, 128, 0, stream>>>(row_start, scol, sval, bufA, bufB, nullptr, N);

    // ---- Attention as GEMM chain ----
    // Q = hidden @ Wq
    mfma_gemm<<<dim3(mb, 1), 256, 0, stream>>>(bufB, Wq, nullptr, Qb,
                                               N, 128, 128, 64, 64, 0, 0);
    // logits = Q @ Bqk (block-diag K^T)
    mfma_gemm<<<dim3(mb, 4), 256, 0, stream>>>(Qb, Bqk, nullptr, logits,
                                               N, 64, 64, 256, 256, 0, 0);
    // P = softmax(scale * logits), in place
    softmax_kernel<<<(N + 3) / 4, 256, 0, stream>>>(logits, N);
    // ctx = P @ Bpv (block-diag V)  -> reuse Qb
    mfma_gemm<<<dim3(mb, 1), 256, 0, stream>>>(logits, Bpv, nullptr, Qb,
                                               N, 256, 256, 64, 64, 0, 0);
    // attended = ctx @ Wo
    mfma_gemm<<<dim3(mb, 2), 256, 0, stream>>>(Qb, Wo, nullptr, bufA,
                                               N, 64, 64, 128, 128, 0, 0);

    // ---- GCN2/3: [lrelu(att@W_mu) | lrelu(att@W_var)] then split spmm ----
    mfma_gemm<<<dim3(mb, 2), 256, 0, stream>>>(bufA, W_mu, W_var, bufB,
                                               N, 128, 128, 64, 128, 1, 1);
    float* out = (float*)d_out;
    spmm_kernel<true><<<N, 128, 0, stream>>>(row_start, scol, sval, bufB,
                                             out, out + (size_t)N * 64, N);
}

// Round 3
// 402.970 us; speedup vs baseline: 1.4425x; 1.2333x over previous
//
#include <hip/hip_runtime.h>
#include <hip/hip_bf16.h>
#include <cstdint>

// ---------------------------------------------------------------------------
// N=50000, E=600000, D_IN=256, H1=128, H2=64, DK=64, HEADS=2 (dk=32).
// R3: bf16 intermediates everywhere (halve traffic); softmax fused into the
// per-head logits GEMM (K=32 block-diagonal); BN=128 MFMA tile.
// ---------------------------------------------------------------------------

typedef __attribute__((ext_vector_type(8))) short short8;
typedef __attribute__((ext_vector_type(4))) float f32x4;
typedef __attribute__((ext_vector_type(4))) unsigned short ushort4_t;

__device__ __forceinline__ unsigned short f2bf(float f) {
    unsigned int u = __builtin_bit_cast(unsigned int, f);
    u += 0x7fffu + ((u >> 16) & 1u);   // RNE
    return (unsigned short)(u >> 16);
}
__device__ __forceinline__ float bf2f(unsigned short v) {
    return __builtin_bit_cast(float, (unsigned int)v << 16);
}

// ---------------- CSR build --------------------------------------------------

__global__ void hist_kernel(const int* __restrict__ rows, int* __restrict__ cnt, int E) {
    int i = blockIdx.x * blockDim.x + threadIdx.x;
    if (i < E) atomicAdd(&cnt[rows[i]], 1);
}

__global__ void scan1_kernel(const int* __restrict__ cnt, int* __restrict__ excl,
                             int* __restrict__ bsum, int N) {
    __shared__ int sh[256];
    int t = threadIdx.x;
    int i = blockIdx.x * 256 + t;
    int v = (i < N) ? cnt[i] : 0;
    sh[t] = v;
    __syncthreads();
    for (int off = 1; off < 256; off <<= 1) {
        int x = (t >= off) ? sh[t - off] : 0;
        __syncthreads();
        sh[t] += x;
        __syncthreads();
    }
    if (i < N) excl[i] = sh[t] - v;
    if (t == 255) bsum[blockIdx.x] = sh[255];
}

__global__ void scan2_kernel(int* __restrict__ bsum, int nb) {
    __shared__ int sh[256];
    int t = threadIdx.x;
    int v = (t < nb) ? bsum[t] : 0;
    sh[t] = v;
    __syncthreads();
    for (int off = 1; off < 256; off <<= 1) {
        int x = (t >= off) ? sh[t - off] : 0;
        __syncthreads();
        sh[t] += x;
        __syncthreads();
    }
    if (t < nb) bsum[t] = sh[t] - v;
}

__global__ void scan3_kernel(const int* __restrict__ excl, const int* __restrict__ bsum,
                             int* __restrict__ row_start, int* __restrict__ cursor,
                             int N, int E) {
    int i = blockIdx.x * 256 + threadIdx.x;
    if (i < N) {
        int v = excl[i] + bsum[i >> 8];
        row_start[i] = v;
        cursor[i] = v;
    }
    if (i == 0) row_start[N] = E;
}

__global__ void scatter_kernel(const int* __restrict__ rows, const int* __restrict__ colsIn,
                               const float* __restrict__ valsIn, int* __restrict__ cursor,
                               int* __restrict__ colsOut, float* __restrict__ valsOut, int E) {
    int i = blockIdx.x * blockDim.x + threadIdx.x;
    if (i < E) {
        int r = rows[i];
        int p = atomicAdd(&cursor[r], 1);
        colsOut[p] = colsIn[i];
        valsOut[p] = valsIn[i];
    }
}

// ---------------- bf16 MFMA GEMM --------------------------------------------
// C[M,*] = act(A[M,K] @ B).  BM=128, BN in {64,128}, BK=64.
// AT in {float, ushort(bf16)}; OT in {float, ushort}; B fp32 unless BF16B.
// DUAL (BN=128): B = [B0 | B1], each [K,64] fp32 (for [W_mu | W_var]).
// BN=128: 2x2 waves, each 64x64 (4x4 frags). BN=64: waves 2x2, each 64x32.

template<int BN, typename AT, typename OT, bool BF16B, bool RELU, bool DUAL>
__global__ __launch_bounds__(256) void mfma_gemm(
    const AT* __restrict__ A, const void* __restrict__ B0v,
    const void* __restrict__ B1v, OT* __restrict__ C,
    int M, int K, int lda, int ldb, int ldc)
{
    constexpr int NT = BN / 32;   // frags per wave in n: 4 (BN=128) or 2 (BN=64)
    __shared__ unsigned short As[128][72];
    __shared__ unsigned short Bs[BN][72];

    const int tid = threadIdx.x;
    const int lane = tid & 63, wave = tid >> 6;
    const int wm = wave & 1, wn = wave >> 1;
    const int quad = lane >> 4, l16 = lane & 15;
    const int r0 = blockIdx.x * 128;
    const int n0 = blockIdx.y * BN;

    f32x4 acc[4][NT];
#pragma unroll
    for (int mt = 0; mt < 4; ++mt)
#pragma unroll
        for (int nt = 0; nt < NT; ++nt)
#pragma unroll
            for (int r = 0; r < 4; ++r) acc[mt][nt][r] = 0.f;

    for (int kc = 0; kc < K; kc += 64) {
        // ---- stage A (128 x 64 bf16) ----
        if constexpr (__is_same(AT, float)) {
#pragma unroll
            for (int i = 0; i < 8; ++i) {
                int f = tid + 256 * i;
                int row = f >> 4;
                int kq = (f & 15) << 2;
                int gr = r0 + row;
                if (gr >= M) gr = M - 1;
                float4 v = *reinterpret_cast<const float4*>(&A[(size_t)gr * lda + kc + kq]);
                ushort4_t pv;
                pv[0] = f2bf(v.x); pv[1] = f2bf(v.y); pv[2] = f2bf(v.z); pv[3] = f2bf(v.w);
                *reinterpret_cast<ushort4_t*>(&As[row][kq]) = pv;
            }
        } else {
#pragma unroll
            for (int i = 0; i < 4; ++i) {
                int f = tid + 256 * i;
                int row = f >> 3;
                int k8 = (f & 7) << 3;
                int gr = r0 + row;
                if (gr >= M) gr = M - 1;
                *reinterpret_cast<short8*>(&As[row][k8]) =
                    *reinterpret_cast<const short8*>(&A[(size_t)gr * lda + kc + k8]);
            }
        }
        // ---- stage B transposed: Bs[n][k] ----
        {
            constexpr int RPI = 256 / BN;           // k-rows per iter
#pragma unroll
            for (int i = 0; i < 64 / RPI; ++i) {
                int n = tid % BN;
                int k = (tid / BN) + RPI * i;
                unsigned short val;
                if constexpr (DUAL) {
                    const float* src = (n < 64) ? (const float*)B0v : (const float*)B1v;
                    val = f2bf(src[(size_t)(kc + k) * 64 + (n & 63)]);
                } else if constexpr (BF16B) {
                    val = ((const unsigned short*)B0v)[(size_t)(kc + k) * ldb + n0 + n];
                } else {
                    val = f2bf(((const float*)B0v)[(size_t)(kc + k) * ldb + n0 + n]);
                }
                Bs[n][k] = val;
            }
        }
        __syncthreads();

#pragma unroll
        for (int ks = 0; ks < 2; ++ks) {
            const int koff = ks * 32 + quad * 8;
            short8 a[4], b[NT];
#pragma unroll
            for (int mt = 0; mt < 4; ++mt)
                a[mt] = *reinterpret_cast<const short8*>(&As[wm * 64 + mt * 16 + l16][koff]);
#pragma unroll
            for (int nt = 0; nt < NT; ++nt)
                b[nt] = *reinterpret_cast<const short8*>(&Bs[wn * (BN / 2) + nt * 16 + l16][koff]);
#pragma unroll
            for (int mt = 0; mt < 4; ++mt)
#pragma unroll
                for (int nt = 0; nt < NT; ++nt)
                    acc[mt][nt] = __builtin_amdgcn_mfma_f32_16x16x32_bf16(
                        a[mt], b[nt], acc[mt][nt], 0, 0, 0);
        }
        __syncthreads();
    }

    // epilogue: C/D layout col=l16, row=quad*4+r
#pragma unroll
    for (int mt = 0; mt < 4; ++mt) {
#pragma unroll
        for (int nt = 0; nt < NT; ++nt) {
            int gc = n0 + wn * (BN / 2) + nt * 16 + l16;
#pragma unroll
            for (int r = 0; r < 4; ++r) {
                int gr = r0 + wm * 64 + mt * 16 + quad * 4 + r;
                if (gr < M) {
                    float v = acc[mt][nt][r];
                    if (RELU) v = v > 0.f ? v : 0.01f * v;
                    if constexpr (__is_same(OT, float))
                        C[(size_t)gr * ldc + gc] = v;
                    else
                        C[(size_t)gr * ldc + gc] = f2bf(v);
                }
            }
        }
    }
}

// ---------------- fused logits + softmax (per head) -------------------------
// grid (mb, 2): head h. P[n, h*128+j] = softmax_j( Q[n,32h:32h+32] @ Ktt[h] ).
// Ktt bf16 [2][128][32] with dk^-0.5 folded. K=32 -> single MFMA per frag.

__global__ __launch_bounds__(256) void logits_softmax_kernel(
    const unsigned short* __restrict__ Q, const unsigned short* __restrict__ Ktt,
    unsigned short* __restrict__ P, int M)
{
    __shared__ unsigned short As[128][40];
    __shared__ unsigned short Bs[128][40];
    __shared__ float redm[2][128];
    __shared__ float reds[2][128];

    const int tid = threadIdx.x;
    const int lane = tid & 63, wave = tid >> 6;
    const int wm = wave & 1, wn = wave >> 1;
    const int quad = lane >> 4, l16 = lane & 15;
    const int r0 = blockIdx.x * 128;
    const int h = blockIdx.y;

#pragma unroll
    for (int i = 0; i < 2; ++i) {
        int f = tid + 256 * i;
        int row = f >> 2, k8 = (f & 3) << 3;
        int gr = r0 + row;
        if (gr >= M) gr = M - 1;
        *reinterpret_cast<short8*>(&As[row][k8]) =
            *reinterpret_cast<const short8*>(&Q[(size_t)gr * 64 + h * 32 + k8]);
    }
#pragma unroll
    for (int i = 0; i < 2; ++i) {
        int f = tid + 256 * i;
        int row = f >> 2, k8 = (f & 3) << 3;
        *reinterpret_cast<short8*>(&Bs[row][k8]) =
            *reinterpret_cast<const short8*>(&Ktt[((size_t)h * 128 + row) * 32 + k8]);
    }
    __syncthreads();

    f32x4 acc[4][4];
    {
        const int koff = quad * 8;
        short8 a[4], b[4];
#pragma unroll
        for (int mt = 0; mt < 4; ++mt)
            a[mt] = *reinterpret_cast<const short8*>(&As[wm * 64 + mt * 16 + l16][koff]);
#pragma unroll
        for (int nt = 0; nt < 4; ++nt)
            b[nt] = *reinterpret_cast<const short8*>(&Bs[wn * 64 + nt * 16 + l16][koff]);
#pragma unroll
        for (int mt = 0; mt < 4; ++mt)
#pragma unroll
            for (int nt = 0; nt < 4; ++nt) {
                f32x4 z; z[0] = 0.f; z[1] = 0.f; z[2] = 0.f; z[3] = 0.f;
                acc[mt][nt] = __builtin_amdgcn_mfma_f32_16x16x32_bf16(a[mt], b[nt], z, 0, 0, 0);
            }
    }

    // row max over this wave's 64 cols, then cross-wave via LDS
#pragma unroll
    for (int mt = 0; mt < 4; ++mt)
#pragma unroll
        for (int r = 0; r < 4; ++r) {
            float mx = fmaxf(fmaxf(acc[mt][0][r], acc[mt][1][r]),
                             fmaxf(acc[mt][2][r], acc[mt][3][r]));
#pragma unroll
            for (int off = 1; off < 16; off <<= 1)
                mx = fmaxf(mx, __shfl_xor(mx, off, 64));
            if (l16 == 0) redm[wn][wm * 64 + mt * 16 + quad * 4 + r] = mx;
        }
    __syncthreads();

#pragma unroll
    for (int mt = 0; mt < 4; ++mt)
#pragma unroll
        for (int r = 0; r < 4; ++r) {
            int lr = wm * 64 + mt * 16 + quad * 4 + r;
            float fm = fmaxf(redm[0][lr], redm[1][lr]);
            float s = 0.f;
#pragma unroll
            for (int nt = 0; nt < 4; ++nt) {
                float e = __expf(acc[mt][nt][r] - fm);
                acc[mt][nt][r] = e;
                s += e;
            }
#pragma unroll
            for (int off = 1; off < 16; off <<= 1)
                s += __shfl_xor(s, off, 64);
            if (l16 == 0) reds[wn][lr] = s;
        }
    __syncthreads();

#pragma unroll
    for (int mt = 0; mt < 4; ++mt)
#pragma unroll
        for (int r = 0; r < 4; ++r) {
            int lr = wm * 64 + mt * 16 + quad * 4 + r;
            int gr = r0 + lr;
            if (gr >= M) continue;
            float inv = 1.0f / (reds[0][lr] + reds[1][lr]);
#pragma unroll
            for (int nt = 0; nt < 4; ++nt) {
                int gc = h * 128 + wn * 64 + nt * 16 + l16;
                P[(size_t)gr * 256 + gc] = f2bf(acc[mt][nt][r] * inv);
            }
        }
}

// ---------------- SpMM over CSR (bf16 X), leaky-relu epilogue ---------------

template<bool SPLIT, typename OT>
__global__ __launch_bounds__(128) void spmm_kernel(
    const int* __restrict__ row_start, const int* __restrict__ cols,
    const float* __restrict__ vals, const unsigned short* __restrict__ X,
    OT* __restrict__ out0, OT* __restrict__ out1, int N)
{
    int r = blockIdx.x;
    int t = threadIdx.x;
    int s = row_start[r];
    int e = row_start[r + 1];
    float acc = 0.f;
    for (int i = s; i < e; ++i) {
        int c = cols[i];
        float v = vals[i];
        acc = fmaf(v, bf2f(X[(size_t)c * 128 + t]), acc);
    }
    float o = acc > 0.f ? acc : 0.01f * acc;
    if constexpr (!SPLIT) {
        out0[(size_t)r * 128 + t] = (OT)f2bf(o);
    } else {
        if (t < 64) out0[(size_t)r * 64 + t] = o;
        else        out1[(size_t)r * 64 + (t - 64)] = o;
    }
}

// ---------------- K/V projection ---------------------------------------------
// Ktt bf16 [2][128][32] (scale folded); Bpv bf16 [256][64] block-diag.

__global__ __launch_bounds__(128) void kv_kernel(
    const float* __restrict__ cond, const float* __restrict__ Wk,
    const float* __restrict__ Wv, unsigned short* __restrict__ Ktt,
    unsigned short* __restrict__ Bpv)
{
    int j = blockIdx.x;      // key 0..127
    int t = threadIdx.x;     // 0..127
    __shared__ float c[128];
    c[t] = cond[j * 128 + t];
    __syncthreads();
    const float* W = (t < 64) ? Wk : Wv;
    int col = t & 63;
    float acc = 0.f;
#pragma unroll 8
    for (int k = 0; k < 128; ++k) acc = fmaf(c[k], W[k * 64 + col], acc);
    int h = col >> 5, d = col & 31;
    if (t < 64) Ktt[((size_t)h * 128 + j) * 32 + d] = f2bf(acc * 0.17677669529663687f);
    else        Bpv[((size_t)(h * 128 + j)) * 64 + col] = f2bf(acc);
}

// ---------------------------------------------------------------------------

extern "C" void kernel_launch(void* const* d_in, const int* in_sizes, int n_in,
                              void* d_out, int out_size, void* d_ws, size_t ws_size,
                              hipStream_t stream)
{
    const float* ns_emb   = (const float*)d_in[0];
    const int*   erows    = (const int*)d_in[1];
    const int*   ecols    = (const int*)d_in[2];
    const float* evals    = (const float*)d_in[3];
    const float* cond     = (const float*)d_in[4];
    const float* W_hidden = (const float*)d_in[5];
    const float* W_mu     = (const float*)d_in[6];
    const float* W_var    = (const float*)d_in[7];
    const float* Wq       = (const float*)d_in[8];
    const float* Wk       = (const float*)d_in[9];
    const float* Wv       = (const float*)d_in[10];
    const float* Wo       = (const float*)d_in[11];

    const int N = in_sizes[0] / 256;  // 50000
    const int E = in_sizes[1];        // 600000

    typedef unsigned short bf16;
    uint8_t* p = (uint8_t*)d_ws;
    auto alloc = [&](size_t bytes) {
        uint8_t* r = p;
        p += (bytes + 255) & ~(size_t)255;
        return r;
    };
    bf16* support1 = (bf16*)alloc(sizeof(bf16) * (size_t)N * 128);
    bf16* hidden   = (bf16*)alloc(sizeof(bf16) * (size_t)N * 128);
    bf16* Qb       = (bf16*)alloc(sizeof(bf16) * (size_t)N * 64);
    bf16* Pbuf     = (bf16*)alloc(sizeof(bf16) * (size_t)N * 256);
    bf16* ctxb     = (bf16*)alloc(sizeof(bf16) * (size_t)N * 64);
    bf16* attnb    = (bf16*)alloc(sizeof(bf16) * (size_t)N * 128);
    bf16* muvarb   = (bf16*)alloc(sizeof(bf16) * (size_t)N * 128);
    bf16* Ktt      = (bf16*)alloc(sizeof(bf16) * 2 * 128 * 32);
    bf16* Bpv      = (bf16*)alloc(sizeof(bf16) * 256 * 64);
    int*  cnt      = (int*)alloc(sizeof(int) * N);
    int*  excl     = (int*)alloc(sizeof(int) * N);
    int*  bsum     = (int*)alloc(sizeof(int) * 256);
    int*  row_start= (int*)alloc(sizeof(int) * (N + 1));
    int*  cursor   = (int*)alloc(sizeof(int) * N);
    int*  scol     = (int*)alloc(sizeof(int) * E);
    float* sval    = (float*)alloc(sizeof(float) * E);

    // ---- CSR build ----
    hipMemsetAsync(cnt, 0, sizeof(int) * N, stream);
    hist_kernel<<<(E + 255) / 256, 256, 0, stream>>>(erows, cnt, E);
    int nb = (N + 255) / 256;
    scan1_kernel<<<nb, 256, 0, stream>>>(cnt, excl, bsum, N);
    scan2_kernel<<<1, 256, 0, stream>>>(bsum, nb);
    scan3_kernel<<<nb, 256, 0, stream>>>(excl, bsum, row_start, cursor, N, E);
    scatter_kernel<<<(E + 255) / 256, 256, 0, stream>>>(erows, ecols, evals, cursor,
                                                        scol, sval, E);

    // ---- K/V operands ----
    hipMemsetAsync(Bpv, 0, sizeof(bf16) * 256 * 64, stream);
    kv_kernel<<<128, 128, 0, stream>>>(cond, Wk, Wv, Ktt, Bpv);

    const int mb = (N + 127) / 128;  // 391

    // ---- GCN1 ----
    mfma_gemm<128, float, bf16, false, true, false><<<dim3(mb, 1), 256, 0, stream>>>(
        ns_emb, W_hidden, nullptr, support1, N, 256, 256, 128, 128);
    spmm_kernel<false, bf16><<<N, 128, 0, stream>>>(row_start, scol, sval,
                                                    support1, hidden, nullptr, N);

    // ---- Attention ----
    mfma_gemm<64, bf16, bf16, false, false, false><<<dim3(mb, 1), 256, 0, stream>>>(
        hidden, Wq, nullptr, Qb, N, 128, 128, 64, 64);
    logits_softmax_kernel<<<dim3(mb, 2), 256, 0, stream>>>(Qb, Ktt, Pbuf, N);
    mfma_gemm<64, bf16, bf16, true, false, false><<<dim3(mb, 1), 256, 0, stream>>>(
        Pbuf, Bpv, nullptr, ctxb, N, 256, 256, 64, 64);
    mfma_gemm<128, bf16, bf16, false, false, false><<<dim3(mb, 1), 256, 0, stream>>>(
        ctxb, Wo, nullptr, attnb, N, 64, 64, 128, 128);

    // ---- GCN2/3 ----
    mfma_gemm<128, bf16, bf16, false, true, true><<<dim3(mb, 1), 256, 0, stream>>>(
        attnb, W_mu, W_var, muvarb, N, 128, 128, 64, 128);
    float* out = (float*)d_out;
    spmm_kernel<true, float><<<N, 128, 0, stream>>>(row_start, scol, sval, muvarb,
                                                    out, out + (size_t)N * 64, N);
}

// Round 4
// 276.062 us; speedup vs baseline: 2.1056x; 1.4597x over previous
//
#include <hip/hip_runtime.h>
#include <hip/hip_bf16.h>
#include <cstdint>

// ---------------------------------------------------------------------------
// N=50000, E=600000, D_IN=256, H1=128, H2=64, DK=64, HEADS=2 (dk=32).
// R4: (1) wave-per-row SpMM with packed (col,val) edges + 4-deep gather
// pipelining; (2) one fused kernel for Q-proj -> logits -> softmax -> P@V
// -> @Wo -> lrelu(@[Wmu|Wvar]) per 128-row tile (all intermediates in LDS);
// (3) weights pre-transposed to bf16 once per launch.
// ---------------------------------------------------------------------------

typedef __attribute__((ext_vector_type(8))) short short8;
typedef __attribute__((ext_vector_type(4))) float f32x4;
typedef __attribute__((ext_vector_type(4))) unsigned short ushort4_t;

__device__ __forceinline__ unsigned short f2bf(float f) {
    unsigned int u = __builtin_bit_cast(unsigned int, f);
    u += 0x7fffu + ((u >> 16) & 1u);   // RNE
    return (unsigned short)(u >> 16);
}
__device__ __forceinline__ float bf2f(unsigned short v) {
    return __builtin_bit_cast(float, (unsigned int)v << 16);
}

// ---------------- CSR build --------------------------------------------------

__global__ void hist_kernel(const int* __restrict__ rows, int* __restrict__ cnt, int E) {
    int i = blockIdx.x * blockDim.x + threadIdx.x;
    if (i < E) atomicAdd(&cnt[rows[i]], 1);
}

__global__ void scan1_kernel(const int* __restrict__ cnt, int* __restrict__ excl,
                             int* __restrict__ bsum, int N) {
    __shared__ int sh[256];
    int t = threadIdx.x;
    int i = blockIdx.x * 256 + t;
    int v = (i < N) ? cnt[i] : 0;
    sh[t] = v;
    __syncthreads();
    for (int off = 1; off < 256; off <<= 1) {
        int x = (t >= off) ? sh[t - off] : 0;
        __syncthreads();
        sh[t] += x;
        __syncthreads();
    }
    if (i < N) excl[i] = sh[t] - v;
    if (t == 255) bsum[blockIdx.x] = sh[255];
}

__global__ void scan2_kernel(int* __restrict__ bsum, int nb) {
    __shared__ int sh[256];
    int t = threadIdx.x;
    int v = (t < nb) ? bsum[t] : 0;
    sh[t] = v;
    __syncthreads();
    for (int off = 1; off < 256; off <<= 1) {
        int x = (t >= off) ? sh[t - off] : 0;
        __syncthreads();
        sh[t] += x;
        __syncthreads();
    }
    if (t < nb) bsum[t] = sh[t] - v;
}

__global__ void scan3_kernel(const int* __restrict__ excl, const int* __restrict__ bsum,
                             int* __restrict__ row_start, int* __restrict__ cursor,
                             int N, int E) {
    int i = blockIdx.x * 256 + threadIdx.x;
    if (i < N) {
        int v = excl[i] + bsum[i >> 8];
        row_start[i] = v;
        cursor[i] = v;
    }
    if (i == 0) row_start[N] = E;
}

__global__ void scatter_kernel(const int* __restrict__ rows, const int* __restrict__ colsIn,
                               const float* __restrict__ valsIn, int* __restrict__ cursor,
                               int2* __restrict__ pack, int E) {
    int i = blockIdx.x * blockDim.x + threadIdx.x;
    if (i < E) {
        int r = rows[i];
        int p = atomicAdd(&cursor[r], 1);
        pack[p] = make_int2(colsIn[i], __float_as_int(valsIn[i]));
    }
}

// ---------------- weight prep: fp32 -> bf16, transposed ---------------------
// WhT[128][256], WqT[64][128], WoT[128][64], WmuT[64][128], WvarT[64][128]

__global__ __launch_bounds__(256) void prep_weights(
    const float* __restrict__ Wh, const float* __restrict__ Wq,
    const float* __restrict__ Wo, const float* __restrict__ Wmu,
    const float* __restrict__ Wvar,
    unsigned short* __restrict__ WhT, unsigned short* __restrict__ WqT,
    unsigned short* __restrict__ WoT, unsigned short* __restrict__ WmuT,
    unsigned short* __restrict__ WvarT)
{
    int idx = blockIdx.x * 256 + threadIdx.x;
    if (idx < 32768) {
        int n = idx & 127, k = idx >> 7;                 // k<256
        WhT[n * 256 + k] = f2bf(Wh[k * 128 + n]);
    } else if (idx < 40960) {
        int i = idx - 32768, n = i & 63, k = i >> 6;     // k<128
        WqT[n * 128 + k] = f2bf(Wq[k * 64 + n]);
    } else if (idx < 49152) {
        int i = idx - 40960, n = i & 127, k = i >> 7;    // k<64
        WoT[n * 64 + k] = f2bf(Wo[k * 128 + n]);
    } else if (idx < 57344) {
        int i = idx - 49152, n = i & 63, k = i >> 6;
        WmuT[n * 128 + k] = f2bf(Wmu[k * 64 + n]);
    } else if (idx < 65536) {
        int i = idx - 57344, n = i & 63, k = i >> 6;
        WvarT[n * 128 + k] = f2bf(Wvar[k * 64 + n]);
    }
}

// ---------------- K/V projection ---------------------------------------------
// Ktt bf16 [2][128][32] (dk^-0.5 folded); Vt bf16 [2][32][128] (d-major).

__global__ __launch_bounds__(128) void kv_kernel(
    const float* __restrict__ cond, const float* __restrict__ Wk,
    const float* __restrict__ Wv, unsigned short* __restrict__ Ktt,
    unsigned short* __restrict__ Vt)
{
    int j = blockIdx.x;      // key 0..127
    int t = threadIdx.x;     // 0..127
    __shared__ float c[128];
    c[t] = cond[j * 128 + t];
    __syncthreads();
    const float* W = (t < 64) ? Wk : Wv;
    int col = t & 63;
    float acc = 0.f;
#pragma unroll 8
    for (int k = 0; k < 128; ++k) acc = fmaf(c[k], W[k * 64 + col], acc);
    int h = col >> 5, d = col & 31;
    if (t < 64) Ktt[((size_t)h * 128 + j) * 32 + d] = f2bf(acc * 0.17677669529663687f);
    else        Vt[((size_t)h * 32 + d) * 128 + j] = f2bf(acc);
}

// ---------------- GCN1 GEMM: support1 = lrelu(ns_emb @ Wh) ------------------
// A fp32 [M,256]; BT bf16 [128][256] (pre-transposed); C bf16 [M,128].

__global__ __launch_bounds__(256) void gcn1_gemm(
    const float* __restrict__ A, const unsigned short* __restrict__ BT,
    unsigned short* __restrict__ C, int M)
{
    __shared__ unsigned short As[128][72];
    __shared__ unsigned short Bs[128][72];

    const int tid = threadIdx.x;
    const int lane = tid & 63, wave = tid >> 6;
    const int wm = wave & 1, wn = wave >> 1;
    const int quad = lane >> 4, l16 = lane & 15;
    const int r0 = blockIdx.x * 128;

    f32x4 acc[4][4];
#pragma unroll
    for (int mt = 0; mt < 4; ++mt)
#pragma unroll
        for (int nt = 0; nt < 4; ++nt)
#pragma unroll
            for (int r = 0; r < 4; ++r) acc[mt][nt][r] = 0.f;

    for (int kc = 0; kc < 256; kc += 64) {
#pragma unroll
        for (int i = 0; i < 8; ++i) {
            int f = tid + 256 * i;
            int row = f >> 4, kq = (f & 15) << 2;
            int gr = r0 + row;
            if (gr >= M) gr = M - 1;
            float4 v = *reinterpret_cast<const float4*>(&A[(size_t)gr * 256 + kc + kq]);
            ushort4_t pv;
            pv[0] = f2bf(v.x); pv[1] = f2bf(v.y); pv[2] = f2bf(v.z); pv[3] = f2bf(v.w);
            *reinterpret_cast<ushort4_t*>(&As[row][kq]) = pv;
        }
#pragma unroll
        for (int i = 0; i < 4; ++i) {
            int f = tid + 256 * i;
            int n = f >> 3, k8 = (f & 7) << 3;
            *reinterpret_cast<short8*>(&Bs[n][k8]) =
                *reinterpret_cast<const short8*>(&BT[(size_t)n * 256 + kc + k8]);
        }
        __syncthreads();

#pragma unroll
        for (int ks = 0; ks < 2; ++ks) {
            const int koff = ks * 32 + quad * 8;
            short8 a[4], b[4];
#pragma unroll
            for (int mt = 0; mt < 4; ++mt)
                a[mt] = *reinterpret_cast<const short8*>(&As[wm * 64 + mt * 16 + l16][koff]);
#pragma unroll
            for (int nt = 0; nt < 4; ++nt)
                b[nt] = *reinterpret_cast<const short8*>(&Bs[wn * 64 + nt * 16 + l16][koff]);
#pragma unroll
            for (int mt = 0; mt < 4; ++mt)
#pragma unroll
                for (int nt = 0; nt < 4; ++nt)
                    acc[mt][nt] = __builtin_amdgcn_mfma_f32_16x16x32_bf16(
                        a[mt], b[nt], acc[mt][nt], 0, 0, 0);
        }
        __syncthreads();
    }

#pragma unroll
    for (int mt = 0; mt < 4; ++mt)
#pragma unroll
        for (int nt = 0; nt < 4; ++nt) {
            int gc = wn * 64 + nt * 16 + l16;
#pragma unroll
            for (int r = 0; r < 4; ++r) {
                int gr = r0 + wm * 64 + mt * 16 + quad * 4 + r;
                if (gr < M) {
                    float v = acc[mt][nt][r];
                    v = v > 0.f ? v : 0.01f * v;
                    C[(size_t)gr * 128 + gc] = f2bf(v);
                }
            }
        }
}

// ---------------- fused attention + muvar kernel ----------------------------
// Per 128-row tile: Q = hidden@Wq; per head: logits -> softmax -> P@V;
// attended = ctx@Wo; muvar = lrelu(attended@[Wmu|Wvar]) -> global bf16.
// LDS: Ap (hidden/P/attended, stride 136), Bp (weights), Cp (Q/ctx, stride 72).

__global__ __launch_bounds__(256) void attn_muvar_kernel(
    const unsigned short* __restrict__ hidden,  // [N,128] bf16
    const unsigned short* __restrict__ WqT,     // [64][128] bf16
    const unsigned short* __restrict__ Ktt,     // [2][128][32] bf16 (scaled)
    const unsigned short* __restrict__ Vt,      // [2][32][128] bf16
    const unsigned short* __restrict__ WoT,     // [128][64] bf16
    const unsigned short* __restrict__ WmuT,    // [64][128] bf16
    const unsigned short* __restrict__ WvarT,   // [64][128] bf16
    unsigned short* __restrict__ muvar,         // [N,128] bf16
    int M)
{
    __shared__ unsigned short Ap[128 * 136];
    __shared__ unsigned short Bp[10240];
    __shared__ unsigned short Cp[128 * 72];
    __shared__ float redm[2][128];
    __shared__ float reds[2][128];

    const int tid = threadIdx.x;
    const int lane = tid & 63, wave = tid >> 6;
    const int wm = wave & 1, wn = wave >> 1;
    const int quad = lane >> 4, l16 = lane & 15;
    const int r0 = blockIdx.x * 128;

    // ---- stage hidden tile -> Ap, WqT -> Bp ----
#pragma unroll
    for (int i = 0; i < 8; ++i) {
        int f = tid + 256 * i;
        int row = f >> 4, k8 = (f & 15) << 3;
        int gr = r0 + row;
        if (gr >= M) gr = M - 1;
        *reinterpret_cast<short8*>(&Ap[row * 136 + k8]) =
            *reinterpret_cast<const short8*>(&hidden[(size_t)gr * 128 + k8]);
    }
#pragma unroll
    for (int i = 0; i < 4; ++i) {
        int f = tid + 256 * i;           // 1024 short8 = 64 rows x 16
        int n = f >> 4, k8 = (f & 15) << 3;
        *reinterpret_cast<short8*>(&Bp[n * 136 + k8]) =
            *reinterpret_cast<const short8*>(&WqT[(size_t)n * 128 + k8]);
    }
    __syncthreads();

    // ---- Q = hidden @ Wq  -> Cp [row][col], col<64 ----
    {
        f32x4 accq[4][2];
#pragma unroll
        for (int mt = 0; mt < 4; ++mt)
#pragma unroll
            for (int nt = 0; nt < 2; ++nt)
#pragma unroll
                for (int r = 0; r < 4; ++r) accq[mt][nt][r] = 0.f;
#pragma unroll
        for (int ks = 0; ks < 4; ++ks) {
            const int koff = ks * 32 + quad * 8;
            short8 a[4], b[2];
#pragma unroll
            for (int mt = 0; mt < 4; ++mt)
                a[mt] = *reinterpret_cast<const short8*>(&Ap[(wm * 64 + mt * 16 + l16) * 136 + koff]);
#pragma unroll
            for (int nt = 0; nt < 2; ++nt)
                b[nt] = *reinterpret_cast<const short8*>(&Bp[(wn * 32 + nt * 16 + l16) * 136 + koff]);
#pragma unroll
            for (int mt = 0; mt < 4; ++mt)
#pragma unroll
                for (int nt = 0; nt < 2; ++nt)
                    accq[mt][nt] = __builtin_amdgcn_mfma_f32_16x16x32_bf16(
                        a[mt], b[nt], accq[mt][nt], 0, 0, 0);
        }
#pragma unroll
        for (int mt = 0; mt < 4; ++mt)
#pragma unroll
            for (int nt = 0; nt < 2; ++nt) {
                int col = wn * 32 + nt * 16 + l16;
#pragma unroll
                for (int r = 0; r < 4; ++r) {
                    int row = wm * 64 + mt * 16 + quad * 4 + r;
                    Cp[row * 72 + col] = f2bf(accq[mt][nt][r]);
                }
            }
    }
    __syncthreads();

    // ---- per-head: logits -> softmax -> P -> ctx ----
    for (int h = 0; h < 2; ++h) {
        // stage Ktt_h -> Bp[key*40+d], Vt_h -> Bp[5120 + d*136 + key]
#pragma unroll
        for (int i = 0; i < 2; ++i) {
            int f = tid + 256 * i;       // 512 short8 = 128 keys x 4
            int key = f >> 2, d8 = (f & 3) << 3;
            *reinterpret_cast<short8*>(&Bp[key * 40 + d8]) =
                *reinterpret_cast<const short8*>(&Ktt[((size_t)h * 128 + key) * 32 + d8]);
        }
#pragma unroll
        for (int i = 0; i < 2; ++i) {
            int f = tid + 256 * i;       // 512 short8 = 32 d x 16
            int d = f >> 4, k8 = (f & 15) << 3;
            *reinterpret_cast<short8*>(&Bp[5120 + d * 136 + k8]) =
                *reinterpret_cast<const short8*>(&Vt[((size_t)h * 32 + d) * 128 + k8]);
        }
        __syncthreads();

        // logits: K=32, output 128x128
        f32x4 accl[4][4];
        {
            short8 a[4], b[4];
#pragma unroll
            for (int mt = 0; mt < 4; ++mt)
                a[mt] = *reinterpret_cast<const short8*>(&Cp[(wm * 64 + mt * 16 + l16) * 72 + h * 32 + quad * 8]);
#pragma unroll
            for (int nt = 0; nt < 4; ++nt)
                b[nt] = *reinterpret_cast<const short8*>(&Bp[(wn * 64 + nt * 16 + l16) * 40 + quad * 8]);
#pragma unroll
            for (int mt = 0; mt < 4; ++mt)
#pragma unroll
                for (int nt = 0; nt < 4; ++nt) {
                    f32x4 z; z[0] = 0.f; z[1] = 0.f; z[2] = 0.f; z[3] = 0.f;
                    accl[mt][nt] = __builtin_amdgcn_mfma_f32_16x16x32_bf16(a[mt], b[nt], z, 0, 0, 0);
                }
        }

        // softmax over 128 keys (this block holds the full row for head h)
#pragma unroll
        for (int mt = 0; mt < 4; ++mt)
#pragma unroll
            for (int r = 0; r < 4; ++r) {
                float mx = fmaxf(fmaxf(accl[mt][0][r], accl[mt][1][r]),
                                 fmaxf(accl[mt][2][r], accl[mt][3][r]));
#pragma unroll
                for (int off = 1; off < 16; off <<= 1)
                    mx = fmaxf(mx, __shfl_xor(mx, off, 64));
                if (l16 == 0) redm[wn][wm * 64 + mt * 16 + quad * 4 + r] = mx;
            }
        __syncthreads();
#pragma unroll
        for (int mt = 0; mt < 4; ++mt)
#pragma unroll
            for (int r = 0; r < 4; ++r) {
                int lr = wm * 64 + mt * 16 + quad * 4 + r;
                float fm = fmaxf(redm[0][lr], redm[1][lr]);
                float s = 0.f;
#pragma unroll
                for (int nt = 0; nt < 4; ++nt) {
                    float e = __expf(accl[mt][nt][r] - fm);
                    accl[mt][nt][r] = e;
                    s += e;
                }
#pragma unroll
                for (int off = 1; off < 16; off <<= 1)
                    s += __shfl_xor(s, off, 64);
                if (l16 == 0) reds[wn][lr] = s;
            }
        __syncthreads();
        // write P -> Ap (hidden is dead)
#pragma unroll
        for (int mt = 0; mt < 4; ++mt)
#pragma unroll
            for (int r = 0; r < 4; ++r) {
                int lr = wm * 64 + mt * 16 + quad * 4 + r;
                float inv = 1.0f / (reds[0][lr] + reds[1][lr]);
#pragma unroll
                for (int nt = 0; nt < 4; ++nt)
                    Ap[lr * 136 + wn * 64 + nt * 16 + l16] = f2bf(accl[mt][nt][r] * inv);
            }
        __syncthreads();

        // ctx_h = P @ V_h : K=128, output 128x32 -> Cp cols h*32..h*32+31
        {
            f32x4 accc[4];
#pragma unroll
            for (int mt = 0; mt < 4; ++mt)
#pragma unroll
                for (int r = 0; r < 4; ++r) accc[mt][r] = 0.f;
#pragma unroll
            for (int ks = 0; ks < 4; ++ks) {
                const int koff = ks * 32 + quad * 8;
                short8 a[4];
#pragma unroll
                for (int mt = 0; mt < 4; ++mt)
                    a[mt] = *reinterpret_cast<const short8*>(&Ap[(wm * 64 + mt * 16 + l16) * 136 + koff]);
                short8 bb = *reinterpret_cast<const short8*>(&Bp[5120 + (wn * 16 + l16) * 136 + koff]);
#pragma unroll
                for (int mt = 0; mt < 4; ++mt)
                    accc[mt] = __builtin_amdgcn_mfma_f32_16x16x32_bf16(a[mt], bb, accc[mt], 0, 0, 0);
            }
#pragma unroll
            for (int mt = 0; mt < 4; ++mt)
#pragma unroll
                for (int r = 0; r < 4; ++r) {
                    int row = wm * 64 + mt * 16 + quad * 4 + r;
                    Cp[row * 72 + h * 32 + wn * 16 + l16] = f2bf(accc[mt][r]);
                }
        }
        __syncthreads();
    }

    // ---- attended = ctx @ Wo : K=64, output 128x128 -> Ap ----
#pragma unroll
    for (int i = 0; i < 4; ++i) {
        int f = tid + 256 * i;           // 1024 short8 = 128 rows x 8
        int n = f >> 3, k8 = (f & 7) << 3;
        *reinterpret_cast<short8*>(&Bp[n * 72 + k8]) =
            *reinterpret_cast<const short8*>(&WoT[(size_t)n * 64 + k8]);
    }
    __syncthreads();
    {
        f32x4 acca[4][4];
#pragma unroll
        for (int mt = 0; mt < 4; ++mt)
#pragma unroll
            for (int nt = 0; nt < 4; ++nt)
#pragma unroll
                for (int r = 0; r < 4; ++r) acca[mt][nt][r] = 0.f;
#pragma unroll
        for (int ks = 0; ks < 2; ++ks) {
            const int koff = ks * 32 + quad * 8;
            short8 a[4], b[4];
#pragma unroll
            for (int mt = 0; mt < 4; ++mt)
                a[mt] = *reinterpret_cast<const short8*>(&Cp[(wm * 64 + mt * 16 + l16) * 72 + koff]);
#pragma unroll
            for (int nt = 0; nt < 4; ++nt)
                b[nt] = *reinterpret_cast<const short8*>(&Bp[(wn * 64 + nt * 16 + l16) * 72 + koff]);
#pragma unroll
            for (int mt = 0; mt < 4; ++mt)
#pragma unroll
                for (int nt = 0; nt < 4; ++nt)
                    acca[mt][nt] = __builtin_amdgcn_mfma_f32_16x16x32_bf16(
                        a[mt], b[nt], acca[mt][nt], 0, 0, 0);
        }
#pragma unroll
        for (int mt = 0; mt < 4; ++mt)
#pragma unroll
            for (int nt = 0; nt < 4; ++nt) {
                int col = wn * 64 + nt * 16 + l16;
#pragma unroll
                for (int r = 0; r < 4; ++r) {
                    int row = wm * 64 + mt * 16 + quad * 4 + r;
                    Ap[row * 136 + col] = f2bf(acca[mt][nt][r]);
                }
            }
    }
    __syncthreads();

    // ---- muvar halves: lrelu(attended @ Wmu|Wvar) -> global ----
    for (int half = 0; half < 2; ++half) {
        const unsigned short* WT = half ? WvarT : WmuT;
#pragma unroll
        for (int i = 0; i < 4; ++i) {
            int f = tid + 256 * i;       // 1024 short8 = 64 rows x 16
            int n = f >> 4, k8 = (f & 15) << 3;
            *reinterpret_cast<short8*>(&Bp[n * 136 + k8]) =
                *reinterpret_cast<const short8*>(&WT[(size_t)n * 128 + k8]);
        }
        __syncthreads();
        f32x4 accm[4][2];
#pragma unroll
        for (int mt = 0; mt < 4; ++mt)
#pragma unroll
            for (int nt = 0; nt < 2; ++nt)
#pragma unroll
                for (int r = 0; r < 4; ++r) accm[mt][nt][r] = 0.f;
#pragma unroll
        for (int ks = 0; ks < 4; ++ks) {
            const int koff = ks * 32 + quad * 8;
            short8 a[4], b[2];
#pragma unroll
            for (int mt = 0; mt < 4; ++mt)
                a[mt] = *reinterpret_cast<const short8*>(&Ap[(wm * 64 + mt * 16 + l16) * 136 + koff]);
#pragma unroll
            for (int nt = 0; nt < 2; ++nt)
                b[nt] = *reinterpret_cast<const short8*>(&Bp[(wn * 32 + nt * 16 + l16) * 136 + koff]);
#pragma unroll
            for (int mt = 0; mt < 4; ++mt)
#pragma unroll
                for (int nt = 0; nt < 2; ++nt)
                    accm[mt][nt] = __builtin_amdgcn_mfma_f32_16x16x32_bf16(
                        a[mt], b[nt], accm[mt][nt], 0, 0, 0);
        }
#pragma unroll
        for (int mt = 0; mt < 4; ++mt)
#pragma unroll
            for (int nt = 0; nt < 2; ++nt) {
                int gc = half * 64 + wn * 32 + nt * 16 + l16;
#pragma unroll
                for (int r = 0; r < 4; ++r) {
                    int gr = r0 + wm * 64 + mt * 16 + quad * 4 + r;
                    if (gr < M) {
                        float v = accm[mt][nt][r];
                        v = v > 0.f ? v : 0.01f * v;
                        muvar[(size_t)gr * 128 + gc] = f2bf(v);
                    }
                }
            }
        __syncthreads();
    }
}

// ---------------- SpMM: one wave per row, 4-deep gather pipeline ------------
// X bf16 [N,128]; each lane covers 2 features (ushort2). pack = (col, valbits).

template<bool SPLIT, typename OT>
__global__ __launch_bounds__(256) void spmm_kernel(
    const int* __restrict__ row_start, const int2* __restrict__ pack,
    const unsigned short* __restrict__ X,
    OT* __restrict__ out0, OT* __restrict__ out1, int N)
{
    const int wave = threadIdx.x >> 6, lane = threadIdx.x & 63;
    int r = blockIdx.x * 4 + wave;
    if (r >= N) return;
    int s = __builtin_amdgcn_readfirstlane(row_start[r]);
    int e = __builtin_amdgcn_readfirstlane(row_start[r + 1]);
    const int fo = lane * 2;

    float ax0 = 0.f, ay0 = 0.f, ax1 = 0.f, ay1 = 0.f;
    float ax2 = 0.f, ay2 = 0.f, ax3 = 0.f, ay3 = 0.f;
    int i = s;
    for (; i + 4 <= e; i += 4) {
        int2 p0 = pack[i], p1 = pack[i + 1], p2 = pack[i + 2], p3 = pack[i + 3];
        unsigned int x0 = *reinterpret_cast<const unsigned int*>(&X[(size_t)p0.x * 128 + fo]);
        unsigned int x1 = *reinterpret_cast<const unsigned int*>(&X[(size_t)p1.x * 128 + fo]);
        unsigned int x2 = *reinterpret_cast<const unsigned int*>(&X[(size_t)p2.x * 128 + fo]);
        unsigned int x3 = *reinterpret_cast<const unsigned int*>(&X[(size_t)p3.x * 128 + fo]);
        float v0 = __int_as_float(p0.y), v1 = __int_as_float(p1.y);
        float v2 = __int_as_float(p2.y), v3 = __int_as_float(p3.y);
        ax0 = fmaf(v0, bf2f((unsigned short)x0), ax0);
        ay0 = fmaf(v0, bf2f((unsigned short)(x0 >> 16)), ay0);
        ax1 = fmaf(v1, bf2f((unsigned short)x1), ax1);
        ay1 = fmaf(v1, bf2f((unsigned short)(x1 >> 16)), ay1);
        ax2 = fmaf(v2, bf2f((unsigned short)x2), ax2);
        ay2 = fmaf(v2, bf2f((unsigned short)(x2 >> 16)), ay2);
        ax3 = fmaf(v3, bf2f((unsigned short)x3), ax3);
        ay3 = fmaf(v3, bf2f((unsigned short)(x3 >> 16)), ay3);
    }
    for (; i < e; ++i) {
        int2 p0 = pack[i];
        unsigned int x0 = *reinterpret_cast<const unsigned int*>(&X[(size_t)p0.x * 128 + fo]);
        float v0 = __int_as_float(p0.y);
        ax0 = fmaf(v0, bf2f((unsigned short)x0), ax0);
        ay0 = fmaf(v0, bf2f((unsigned short)(x0 >> 16)), ay0);
    }
    float ox = (ax0 + ax1) + (ax2 + ax3);
    float oy = (ay0 + ay1) + (ay2 + ay3);
    ox = ox > 0.f ? ox : 0.01f * ox;
    oy = oy > 0.f ? oy : 0.01f * oy;

    if constexpr (!SPLIT) {
        unsigned int w = (unsigned int)f2bf(ox) | ((unsigned int)f2bf(oy) << 16);
        *reinterpret_cast<unsigned int*>(&out0[(size_t)r * 128 + fo]) = w;
    } else {
        if (lane < 32) {
            float2 w = make_float2(ox, oy);
            *reinterpret_cast<float2*>(&out0[(size_t)r * 64 + fo]) = w;
        } else {
            float2 w = make_float2(ox, oy);
            *reinterpret_cast<float2*>(&out1[(size_t)r * 64 + (fo - 64)]) = w;
        }
    }
}

// ---------------------------------------------------------------------------

extern "C" void kernel_launch(void* const* d_in, const int* in_sizes, int n_in,
                              void* d_out, int out_size, void* d_ws, size_t ws_size,
                              hipStream_t stream)
{
    const float* ns_emb   = (const float*)d_in[0];
    const int*   erows    = (const int*)d_in[1];
    const int*   ecols    = (const int*)d_in[2];
    const float* evals    = (const float*)d_in[3];
    const float* cond     = (const float*)d_in[4];
    const float* W_hidden = (const float*)d_in[5];
    const float* W_mu     = (const float*)d_in[6];
    const float* W_var    = (const float*)d_in[7];
    const float* Wq       = (const float*)d_in[8];
    const float* Wk       = (const float*)d_in[9];
    const float* Wv       = (const float*)d_in[10];
    const float* Wo       = (const float*)d_in[11];

    const int N = in_sizes[0] / 256;  // 50000
    const int E = in_sizes[1];        // 600000

    typedef unsigned short bf16;
    uint8_t* p = (uint8_t*)d_ws;
    auto alloc = [&](size_t bytes) {
        uint8_t* r = p;
        p += (bytes + 255) & ~(size_t)255;
        return r;
    };
    bf16* support1 = (bf16*)alloc(sizeof(bf16) * (size_t)N * 128);
    bf16* hidden   = (bf16*)alloc(sizeof(bf16) * (size_t)N * 128);
    bf16* muvarb   = (bf16*)alloc(sizeof(bf16) * (size_t)N * 128);
    bf16* Ktt      = (bf16*)alloc(sizeof(bf16) * 2 * 128 * 32);
    bf16* Vt       = (bf16*)alloc(sizeof(bf16) * 2 * 32 * 128);
    bf16* WhT      = (bf16*)alloc(sizeof(bf16) * 128 * 256);
    bf16* WqT      = (bf16*)alloc(sizeof(bf16) * 64 * 128);
    bf16* WoT      = (bf16*)alloc(sizeof(bf16) * 128 * 64);
    bf16* WmuT     = (bf16*)alloc(sizeof(bf16) * 64 * 128);
    bf16* WvarT    = (bf16*)alloc(sizeof(bf16) * 64 * 128);
    int*  cnt      = (int*)alloc(sizeof(int) * N);
    int*  excl     = (int*)alloc(sizeof(int) * N);
    int*  bsum     = (int*)alloc(sizeof(int) * 256);
    int*  row_start= (int*)alloc(sizeof(int) * (N + 1));
    int*  cursor   = (int*)alloc(sizeof(int) * N);
    int2* pack     = (int2*)alloc(sizeof(int2) * E);

    // ---- CSR build ----
    hipMemsetAsync(cnt, 0, sizeof(int) * N, stream);
    hist_kernel<<<(E + 255) / 256, 256, 0, stream>>>(erows, cnt, E);
    int nb = (N + 255) / 256;
    scan1_kernel<<<nb, 256, 0, stream>>>(cnt, excl, bsum, N);
    scan2_kernel<<<1, 256, 0, stream>>>(bsum, nb);
    scan3_kernel<<<nb, 256, 0, stream>>>(excl, bsum, row_start, cursor, N, E);
    scatter_kernel<<<(E + 255) / 256, 256, 0, stream>>>(erows, ecols, evals, cursor, pack, E);

    // ---- weight prep + K/V ----
    prep_weights<<<256, 256, 0, stream>>>(W_hidden, Wq, Wo, W_mu, W_var,
                                          WhT, WqT, WoT, WmuT, WvarT);
    kv_kernel<<<128, 128, 0, stream>>>(cond, Wk, Wv, Ktt, Vt);

    const int mb = (N + 127) / 128;  // 391

    // ---- GCN1 ----
    gcn1_gemm<<<mb, 256, 0, stream>>>(ns_emb, WhT, support1, N);
    spmm_kernel<false, bf16><<<(N + 3) / 4, 256, 0, stream>>>(
        row_start, pack, support1, hidden, nullptr, N);

    // ---- fused attention -> muvar ----
    attn_muvar_kernel<<<mb, 256, 0, stream>>>(hidden, WqT, Ktt, Vt, WoT,
                                              WmuT, WvarT, muvarb, N);

    // ---- final SpMM (split mu/var, fp32 out) ----
    float* out = (float*)d_out;
    spmm_kernel<true, float><<<(N + 3) / 4, 256, 0, stream>>>(
        row_start, pack, muvarb, out, out + (size_t)N * 64, N);
}